// Round 9
// baseline (423.242 us; speedup 1.0000x reference)
//
#include <hip/hip_runtime.h>
#include <hip/hip_bf16.h>

// GNN decoder: 2x (GCNConv -> BatchNorm[-> ReLU]) on N=100000 nodes, E=1.6M edges.
// Round 9 (= r8 with compile fix): __builtin_nontemporal_load needs a native
// vector type, not HIP's int4 class -> use ext_vector_type(4) int.
// (a) NT streaming loads of src/dst in degree/csr kernels -- r7 profile showed
// 72MB writeback for a 6.4MB csr array (read stream evicted partially-filled
// dirty lines from XCD L2). (b) Role-split block fusion: csr_build+GEMM1 in one
// launch; wreorder rides on the degree launch. NT csr_src reads in aggregates.
// Carries: one-wave-per-node aggregates at ~3.8TB/s gather ceiling (r5/r7),
// stats+bnprep ticket fusion (r7), XCD-affine CSR build (r4), dinv-prescaled
// GEMMs (r4), bf16 intermediates + no-LDS MFMA GEMMs (r3), CSR gather (r2),
// BN bias cancellation (r1).

#define IN_C 128
#define HID_C 128
#define OUT_C2 64
#define BN_EPS 1e-5f
#define NGROUPS 8
#define NB_CSR 2048
#define NB_DEG 2048

typedef __attribute__((ext_vector_type(8))) short short8v;
typedef __attribute__((ext_vector_type(4))) float float4v;
typedef __attribute__((ext_vector_type(4))) int int4v;

__device__ inline ushort f2bf(float f) {
    union { float f; unsigned u; } x; x.f = f;
    return (ushort)((x.u + 0x7fffu + ((x.u >> 16) & 1u)) >> 16);  // RNE
}
__device__ inline float bf2f(ushort u) {
    union { unsigned u; float f; } x; x.u = ((unsigned)u) << 16;
    return x.f;
}

// zero stats1/stats2/sc/sh/tickets (ws[0:770)) + deg (N int) in one launch
__global__ void init_kernel(float* __restrict__ ws, int* __restrict__ deg, int N) {
    int i = blockIdx.x * blockDim.x + threadIdx.x;
    if (i < 770) ws[i] = 0.0f;
    if (i < N) deg[i] = 0;
}

// W[128][OC] f32 -> fragment-ordered bf16
template <int OC>
__device__ inline void wreorder_impl(const float* __restrict__ W,
                                     ushort* __restrict__ wfrag, int t) {
    constexpr int NCT = OC / 16;
    int lane = t & 63;
    int rest = t >> 6;
    int ct = rest % NCT;
    int kk = rest / NCT;
    int col = ct * 16 + (lane & 15);
    int krow = kk * 32 + (lane >> 4) * 8;
    ushort tmp[8];
    #pragma unroll
    for (int e = 0; e < 8; ++e)
        tmp[e] = f2bf(W[(size_t)(krow + e) * OC + col]);
    uint4 st;
    st.x = (uint)tmp[0] | ((uint)tmp[1] << 16);
    st.y = (uint)tmp[2] | ((uint)tmp[3] << 16);
    st.z = (uint)tmp[4] | ((uint)tmp[5] << 16);
    st.w = (uint)tmp[6] | ((uint)tmp[7] << 16);
    *(uint4*)&wfrag[(size_t)t * 8] = st;
}

// Grouped degree histogram (blocks [0,NB_DEG)) + weight reorder (12 blocks).
// NT streaming reads of dst so the histogram lines stay resident in L2.
__global__ __launch_bounds__(256) void degree_wre_kernel(
    const int* __restrict__ dst, int* __restrict__ deg, int E, int gsz,
    const float* __restrict__ W1, const float* __restrict__ W2,
    ushort* __restrict__ wf1, ushort* __restrict__ wf2)
{
    if (blockIdx.x >= NB_DEG) {
        int b = blockIdx.x - NB_DEG;
        if (b < 8) wreorder_impl<HID_C>(W1, wf1, b * 256 + threadIdx.x);
        else       wreorder_impl<OUT_C2>(W2, wf2, (b - 8) * 256 + threadIdx.x);
        return;
    }
    int g = blockIdx.x & (NGROUPS - 1);
    int bi = blockIdx.x / NGROUPS;
    int bpg = NB_DEG / NGROUPS;
    int lo = g * gsz, hi = lo + gsz;
    int E4 = E & ~3;
    int stride = bpg * 256 * 4;
    for (int i = (bi * 256 + threadIdx.x) * 4; i < E4; i += stride) {
        int4v d = __builtin_nontemporal_load((const int4v*)&dst[i]);
        if (d.x >= lo && d.x < hi) atomicAdd(&deg[d.x], 1);
        if (d.y >= lo && d.y < hi) atomicAdd(&deg[d.y], 1);
        if (d.z >= lo && d.z < hi) atomicAdd(&deg[d.z], 1);
        if (d.w >= lo && d.w < hi) atomicAdd(&deg[d.w], 1);
    }
    if (bi == 0 && threadIdx.x < (E & 3)) {
        int d = dst[E4 + threadIdx.x];
        if (d >= lo && d < hi) atomicAdd(&deg[d], 1);
    }
}

// exclusive scan of deg[N] -> row_ptr (per-tile) + tile sums; also emits dinv
__global__ __launch_bounds__(256) void scan1_kernel(const int* __restrict__ in,
                                                    int* __restrict__ out,
                                                    int* __restrict__ tilesums,
                                                    float* __restrict__ dinv, int n)
{
    __shared__ int sdata[256];
    int t = threadIdx.x;
    int idx = blockIdx.x * 1024 + t * 4;
    int4 v = make_int4(0, 0, 0, 0);
    if (idx + 3 < n) v = *(const int4*)&in[idx];
    else {
        if (idx < n)     v.x = in[idx];
        if (idx + 1 < n) v.y = in[idx + 1];
        if (idx + 2 < n) v.z = in[idx + 2];
        if (idx + 3 < n) v.w = in[idx + 3];
    }
    if (idx + 3 < n) {
        *(float4*)&dinv[idx] = make_float4(rsqrtf((float)v.x + 1.0f),
                                           rsqrtf((float)v.y + 1.0f),
                                           rsqrtf((float)v.z + 1.0f),
                                           rsqrtf((float)v.w + 1.0f));
    } else {
        if (idx < n)     dinv[idx]     = rsqrtf((float)v.x + 1.0f);
        if (idx + 1 < n) dinv[idx + 1] = rsqrtf((float)v.y + 1.0f);
        if (idx + 2 < n) dinv[idx + 2] = rsqrtf((float)v.z + 1.0f);
        if (idx + 3 < n) dinv[idx + 3] = rsqrtf((float)v.w + 1.0f);
    }
    int s1 = v.x, s2 = s1 + v.y, s3 = s2 + v.z, s4 = s3 + v.w;
    sdata[t] = s4;
    __syncthreads();
    for (int off = 1; off < 256; off <<= 1) {
        int val = (t >= off) ? sdata[t - off] : 0;
        __syncthreads();
        sdata[t] += val;
        __syncthreads();
    }
    int prev = sdata[t] - s4;
    if (idx < n)     out[idx]     = prev;
    if (idx + 1 < n) out[idx + 1] = prev + s1;
    if (idx + 2 < n) out[idx + 2] = prev + s2;
    if (idx + 3 < n) out[idx + 3] = prev + s3;
    if (t == 255) tilesums[blockIdx.x] = sdata[255];
}

// finalize: every block redundantly scans tilesums (<=256) in LDS, then adds
// tile offsets to row_ptr and seeds cursor.
__global__ __launch_bounds__(256) void scan_fin_kernel(
    int* __restrict__ row_ptr, int* __restrict__ cursor,
    const int* __restrict__ tilesums, int numTiles, int n)
{
    __shared__ int sd[256];
    __shared__ int ex[256];
    int t = threadIdx.x;
    int v = (t < numTiles) ? tilesums[t] : 0;
    sd[t] = v;
    __syncthreads();
    for (int off = 1; off < 256; off <<= 1) {
        int val = (t >= off) ? sd[t - off] : 0;
        __syncthreads();
        sd[t] += val;
        __syncthreads();
    }
    ex[t] = sd[t] - v;
    int total = sd[255];
    __syncthreads();
    int i = blockIdx.x * 256 + t;
    if (i == 0) row_ptr[n] = total;
    if (i < n) {
        int rp = row_ptr[i] + ex[i >> 10];
        row_ptr[i] = rp;
        cursor[i] = rp;
    }
}

// MFMA GEMM body: Y[N][OC] bf16 = dinv[row] * (A @ W). No LDS.
template <int OC, bool BN_IN>
__device__ inline void gemm_body(
    const void* __restrict__ Xv, const ushort* __restrict__ wfrag,
    ushort* __restrict__ Y, const float* __restrict__ dinv,
    const float* __restrict__ sc, const float* __restrict__ sh,
    int N, int wave, int lane)
{
    constexpr int NCT = OC / 16;
    int row16 = wave * 16;
    if (row16 >= N) return;
    int r = lane & 15;
    int g = lane >> 4;
    int row = row16 + r;

    float4v acc[NCT];
    #pragma unroll
    for (int ct = 0; ct < NCT; ++ct) acc[ct] = (float4v){0.f, 0.f, 0.f, 0.f};

    const short8v* wf = (const short8v*)wfrag;

    #pragma unroll
    for (int kk = 0; kk < 4; ++kk) {
        int k0 = kk * 32 + g * 8;
        short8v a;
        if constexpr (!BN_IN) {
            const float* xp = (const float*)Xv + (size_t)row * 128 + k0;
            float4 x0 = *(const float4*)xp;
            float4 x1 = *(const float4*)(xp + 4);
            a[0] = (short)f2bf(x0.x); a[1] = (short)f2bf(x0.y);
            a[2] = (short)f2bf(x0.z); a[3] = (short)f2bf(x0.w);
            a[4] = (short)f2bf(x1.x); a[5] = (short)f2bf(x1.y);
            a[6] = (short)f2bf(x1.z); a[7] = (short)f2bf(x1.w);
        } else {
            const ushort* xp = (const ushort*)Xv + (size_t)row * 128 + k0;
            uint4 v = *(const uint4*)xp;
            float4 s0 = *(const float4*)&sc[k0];
            float4 s1 = *(const float4*)&sc[k0 + 4];
            float4 h0 = *(const float4*)&sh[k0];
            float4 h1 = *(const float4*)&sh[k0 + 4];
            a[0] = (short)f2bf(fmaxf(fmaf(bf2f((ushort)(v.x & 0xffff)), s0.x, h0.x), 0.f));
            a[1] = (short)f2bf(fmaxf(fmaf(bf2f((ushort)(v.x >> 16)),    s0.y, h0.y), 0.f));
            a[2] = (short)f2bf(fmaxf(fmaf(bf2f((ushort)(v.y & 0xffff)), s0.z, h0.z), 0.f));
            a[3] = (short)f2bf(fmaxf(fmaf(bf2f((ushort)(v.y >> 16)),    s0.w, h0.w), 0.f));
            a[4] = (short)f2bf(fmaxf(fmaf(bf2f((ushort)(v.z & 0xffff)), s1.x, h1.x), 0.f));
            a[5] = (short)f2bf(fmaxf(fmaf(bf2f((ushort)(v.z >> 16)),    s1.y, h1.y), 0.f));
            a[6] = (short)f2bf(fmaxf(fmaf(bf2f((ushort)(v.w & 0xffff)), s1.z, h1.z), 0.f));
            a[7] = (short)f2bf(fmaxf(fmaf(bf2f((ushort)(v.w >> 16)),    s1.w, h1.w), 0.f));
        }
        #pragma unroll
        for (int ct = 0; ct < NCT; ++ct) {
            short8v b = wf[((size_t)(kk * NCT + ct)) * 64 + lane];
            acc[ct] = __builtin_amdgcn_mfma_f32_16x16x32_bf16(a, b, acc[ct], 0, 0, 0);
        }
    }
    float di[4];
    #pragma unroll
    for (int i = 0; i < 4; ++i) di[i] = dinv[row16 + g * 4 + i];
    #pragma unroll
    for (int ct = 0; ct < NCT; ++ct) {
        #pragma unroll
        for (int i = 0; i < 4; ++i) {
            int orow = row16 + g * 4 + i;
            Y[(size_t)orow * OC + ct * 16 + r] = f2bf(acc[ct][i] * di[i]);
        }
    }
}

// Fused: blocks [0,NB_CSR) grouped CSR placement (NT streaming reads);
// blocks [NB_CSR,..) GEMM1. Independent work, one dispatch -> latency-bound
// csr overlaps MFMA-bound gemm.
__global__ __launch_bounds__(256) void csr_gemm1_kernel(
    const int* __restrict__ src, const int* __restrict__ dst,
    int* __restrict__ cursor, int* __restrict__ csr_src, int E, int gsz,
    const float* __restrict__ X, const ushort* __restrict__ wfrag,
    ushort* __restrict__ Y, const float* __restrict__ dinv, int N)
{
    if (blockIdx.x >= NB_CSR) {
        int wave = (((int)blockIdx.x - NB_CSR) * 256 + threadIdx.x) >> 6;
        gemm_body<HID_C, false>(X, wfrag, Y, dinv, nullptr, nullptr,
                                N, wave, threadIdx.x & 63);
        return;
    }
    int g = blockIdx.x & (NGROUPS - 1);
    int bi = blockIdx.x / NGROUPS;
    int bpg = NB_CSR / NGROUPS;
    int lo = g * gsz, hi = lo + gsz;
    int E4 = E & ~3;
    int stride = bpg * 256 * 4;
    for (int i = (bi * 256 + threadIdx.x) * 4; i < E4; i += stride) {
        int4v d = __builtin_nontemporal_load((const int4v*)&dst[i]);
        int4v s = __builtin_nontemporal_load((const int4v*)&src[i]);
        if (d.x >= lo && d.x < hi) csr_src[atomicAdd(&cursor[d.x], 1)] = s.x;
        if (d.y >= lo && d.y < hi) csr_src[atomicAdd(&cursor[d.y], 1)] = s.y;
        if (d.z >= lo && d.z < hi) csr_src[atomicAdd(&cursor[d.z], 1)] = s.z;
        if (d.w >= lo && d.w < hi) csr_src[atomicAdd(&cursor[d.w], 1)] = s.w;
    }
    if (bi == 0 && threadIdx.x < (E & 3)) {
        int i = E4 + threadIdx.x;
        int d = dst[i];
        if (d >= lo && d < hi) csr_src[atomicAdd(&cursor[d], 1)] = src[i];
    }
}

// Standalone GEMM (layer 2)
template <int OC, bool BN_IN>
__global__ __launch_bounds__(256) void mfma_gemm_kernel(
    const void* __restrict__ Xv, const ushort* __restrict__ wfrag,
    ushort* __restrict__ Y, const float* __restrict__ dinv,
    const float* __restrict__ sc, const float* __restrict__ sh, int N)
{
    int wave = (blockIdx.x * 256 + threadIdx.x) >> 6;
    gemm_body<OC, BN_IN>(Xv, wfrag, Y, dinv, sc, sh, N, wave, threadIdx.x & 63);
}

// One wave per node, 2x-unrolled gather, bf16 out. NT csr_src reads (read-once
// stream) keep L2 free for h-row gathers.
template <int C>
__global__ __launch_bounds__(256) void aggregate_kernel(
    const ushort* __restrict__ h, const int* __restrict__ row_ptr,
    const int* __restrict__ csr_src, const float* __restrict__ dinv,
    ushort* __restrict__ out, int N)
{
    constexpr int TPN = C / 8;
    constexpr int PAR = 64 / TPN;
    int wid = (blockIdx.x * 256 + threadIdx.x) >> 6;
    if (wid >= N) return;
    int lane = threadIdx.x & 63;
    int part = lane / TPN;
    int c0 = (lane % TPN) * 8;
    float acc[8] = {0.f, 0.f, 0.f, 0.f, 0.f, 0.f, 0.f, 0.f};

    uint4 vself = make_uint4(0u, 0u, 0u, 0u);
    if (part == 0) vself = *(const uint4*)&h[(size_t)wid * C + c0];

    int e = row_ptr[wid] + part;
    int e1 = row_ptr[wid + 1];
    for (; e + PAR < e1; e += 2 * PAR) {
        int s0 = __builtin_nontemporal_load(&csr_src[e]);
        int s1 = __builtin_nontemporal_load(&csr_src[e + PAR]);
        uint4 v0 = *(const uint4*)&h[(size_t)s0 * C + c0];
        uint4 v1 = *(const uint4*)&h[(size_t)s1 * C + c0];
        acc[0] += bf2f((ushort)(v0.x & 0xffff)) + bf2f((ushort)(v1.x & 0xffff));
        acc[1] += bf2f((ushort)(v0.x >> 16))    + bf2f((ushort)(v1.x >> 16));
        acc[2] += bf2f((ushort)(v0.y & 0xffff)) + bf2f((ushort)(v1.y & 0xffff));
        acc[3] += bf2f((ushort)(v0.y >> 16))    + bf2f((ushort)(v1.y >> 16));
        acc[4] += bf2f((ushort)(v0.z & 0xffff)) + bf2f((ushort)(v1.z & 0xffff));
        acc[5] += bf2f((ushort)(v0.z >> 16))    + bf2f((ushort)(v1.z >> 16));
        acc[6] += bf2f((ushort)(v0.w & 0xffff)) + bf2f((ushort)(v1.w & 0xffff));
        acc[7] += bf2f((ushort)(v0.w >> 16))    + bf2f((ushort)(v1.w >> 16));
    }
    if (e < e1) {
        int s = __builtin_nontemporal_load(&csr_src[e]);
        uint4 v = *(const uint4*)&h[(size_t)s * C + c0];
        acc[0] += bf2f((ushort)(v.x & 0xffff));
        acc[1] += bf2f((ushort)(v.x >> 16));
        acc[2] += bf2f((ushort)(v.y & 0xffff));
        acc[3] += bf2f((ushort)(v.y >> 16));
        acc[4] += bf2f((ushort)(v.z & 0xffff));
        acc[5] += bf2f((ushort)(v.z >> 16));
        acc[6] += bf2f((ushort)(v.w & 0xffff));
        acc[7] += bf2f((ushort)(v.w >> 16));
    }
    if (part == 0) {
        acc[0] += bf2f((ushort)(vself.x & 0xffff));
        acc[1] += bf2f((ushort)(vself.x >> 16));
        acc[2] += bf2f((ushort)(vself.y & 0xffff));
        acc[3] += bf2f((ushort)(vself.y >> 16));
        acc[4] += bf2f((ushort)(vself.z & 0xffff));
        acc[5] += bf2f((ushort)(vself.z >> 16));
        acc[6] += bf2f((ushort)(vself.w & 0xffff));
        acc[7] += bf2f((ushort)(vself.w >> 16));
    }
    #pragma unroll
    for (int off = TPN; off < 64; off <<= 1) {
        #pragma unroll
        for (int j = 0; j < 8; ++j)
            acc[j] += __shfl_xor(acc[j], off, 64);
    }
    if (part == 0) {
        float dd = dinv[wid];
        uint4 st;
        #pragma unroll
        for (int j = 0; j < 8; ++j) acc[j] *= dd;
        st.x = (uint)f2bf(acc[0]) | ((uint)f2bf(acc[1]) << 16);
        st.y = (uint)f2bf(acc[2]) | ((uint)f2bf(acc[3]) << 16);
        st.z = (uint)f2bf(acc[4]) | ((uint)f2bf(acc[5]) << 16);
        st.w = (uint)f2bf(acc[6]) | ((uint)f2bf(acc[7]) << 16);
        *(uint4*)&out[(size_t)wid * C + c0] = st;
    }
}

// Per-channel sum & sumsq over bf16 rows + last-block BN scale/shift prep.
template <int C>
__global__ __launch_bounds__(256) void stats_prep_kernel(
    const ushort* __restrict__ h, float* __restrict__ sums /* [2C] */,
    const float* __restrict__ gamma, const float* __restrict__ beta,
    float* __restrict__ sc, float* __restrict__ sh,
    int* __restrict__ ticket, int nblocks, int N)
{
    constexpr int CG = C / 8;
    constexpr int RPB = 256 / CG;
    __shared__ float red[RPB][CG][16];
    __shared__ bool lastblk;
    int tid = threadIdx.x;
    int cg = tid % CG, rg = tid / CG;
    int c0 = cg * 8;
    float s[8] = {0.f,0.f,0.f,0.f,0.f,0.f,0.f,0.f};
    float q[8] = {0.f,0.f,0.f,0.f,0.f,0.f,0.f,0.f};
    for (int r = blockIdx.x * RPB + rg; r < N; r += gridDim.x * RPB) {
        uint4 v = *(const uint4*)&h[(size_t)r * C + c0];
        float f0 = bf2f((ushort)(v.x & 0xffff)), f1 = bf2f((ushort)(v.x >> 16));
        float f2 = bf2f((ushort)(v.y & 0xffff)), f3 = bf2f((ushort)(v.y >> 16));
        float f4 = bf2f((ushort)(v.z & 0xffff)), f5 = bf2f((ushort)(v.z >> 16));
        float f6 = bf2f((ushort)(v.w & 0xffff)), f7 = bf2f((ushort)(v.w >> 16));
        s[0]+=f0; s[1]+=f1; s[2]+=f2; s[3]+=f3; s[4]+=f4; s[5]+=f5; s[6]+=f6; s[7]+=f7;
        q[0]=fmaf(f0,f0,q[0]); q[1]=fmaf(f1,f1,q[1]); q[2]=fmaf(f2,f2,q[2]); q[3]=fmaf(f3,f3,q[3]);
        q[4]=fmaf(f4,f4,q[4]); q[5]=fmaf(f5,f5,q[5]); q[6]=fmaf(f6,f6,q[6]); q[7]=fmaf(f7,f7,q[7]);
    }
    #pragma unroll
    for (int j = 0; j < 8; ++j) { red[rg][cg][j] = s[j]; red[rg][cg][8 + j] = q[j]; }
    __syncthreads();
    if (rg == 0) {
        float a[16];
        #pragma unroll
        for (int i = 0; i < 16; ++i) a[i] = red[0][cg][i];
        for (int r2 = 1; r2 < RPB; ++r2)
            #pragma unroll
            for (int i = 0; i < 16; ++i) a[i] += red[r2][cg][i];
        #pragma unroll
        for (int j = 0; j < 8; ++j) {
            atomicAdd(&sums[c0 + j], a[j]);
            atomicAdd(&sums[C + c0 + j], a[8 + j]);
        }
    }
    __syncthreads();
    if (tid == 0) {
        __threadfence();
        int old = atomicAdd(ticket, 1);
        lastblk = (old == nblocks - 1);
    }
    __syncthreads();
    if (lastblk && tid < C) {
        float sv = atomicAdd(&sums[tid], 0.0f);        // coherent reads
        float qv = atomicAdd(&sums[C + tid], 0.0f);
        float invN = 1.0f / (float)N;
        float mu = sv * invN;
        float var = qv * invN - mu * mu;
        float scl = rsqrtf(var + BN_EPS) * gamma[tid];
        sc[tid] = scl;
        sh[tid] = beta[tid] - mu * scl;
    }
}

// BN2 apply: bf16 in -> f32 out, 8 channels per thread
__global__ void bn_apply_kernel(const ushort* __restrict__ in, float* __restrict__ out,
                                const float* __restrict__ sc, const float* __restrict__ sh,
                                int N)
{
    int total = N * (OUT_C2 / 8);
    int i = blockIdx.x * blockDim.x + threadIdx.x;
    int stride = gridDim.x * blockDim.x;
    for (; i < total; i += stride) {
        int c0 = (i & 7) * 8;
        uint4 v = *(const uint4*)&in[(size_t)i * 8];
        float4 s0 = *(const float4*)&sc[c0];
        float4 s1 = *(const float4*)&sc[c0 + 4];
        float4 h0 = *(const float4*)&sh[c0];
        float4 h1 = *(const float4*)&sh[c0 + 4];
        float4 o0, o1;
        o0.x = fmaf(bf2f((ushort)(v.x & 0xffff)), s0.x, h0.x);
        o0.y = fmaf(bf2f((ushort)(v.x >> 16)),    s0.y, h0.y);
        o0.z = fmaf(bf2f((ushort)(v.y & 0xffff)), s0.z, h0.z);
        o0.w = fmaf(bf2f((ushort)(v.y >> 16)),    s0.w, h0.w);
        o1.x = fmaf(bf2f((ushort)(v.z & 0xffff)), s1.x, h1.x);
        o1.y = fmaf(bf2f((ushort)(v.z >> 16)),    s1.y, h1.y);
        o1.z = fmaf(bf2f((ushort)(v.w & 0xffff)), s1.z, h1.z);
        o1.w = fmaf(bf2f((ushort)(v.w >> 16)),    s1.w, h1.w);
        *(float4*)&out[(size_t)i * 8] = o0;
        *(float4*)&out[(size_t)i * 8 + 4] = o1;
    }
}

extern "C" void kernel_launch(void* const* d_in, const int* in_sizes, int n_in,
                              void* d_out, int out_size, void* d_ws, size_t ws_size,
                              hipStream_t stream) {
    const float* x      = (const float*)d_in[0];
    const int*   ei     = (const int*)d_in[1];
    const float* W1     = (const float*)d_in[2];
    // d_in[3] = b1: cancels in BN1 -> skipped
    const float* gamma1 = (const float*)d_in[4];
    const float* beta1  = (const float*)d_in[5];
    const float* W2     = (const float*)d_in[6];
    // d_in[7] = b2: cancels in BN2 -> skipped
    const float* gamma2 = (const float*)d_in[8];
    const float* beta2  = (const float*)d_in[9];

    const int N = in_sizes[0] / IN_C;   // 100000 (divisible by 16)
    const int E = in_sizes[1] / 2;      // 1600000
    const int* src = ei;
    const int* dst = ei + E;
    const int gsz = (N + NGROUPS - 1) / NGROUPS;

    // ws layout (4B words):
    float* ws      = (float*)d_ws;
    float* stats1  = ws;                     // 256
    float* stats2  = ws + 256;               // 128
    float* sc1     = ws + 384;               // 128
    float* sh1     = ws + 512;               // 128
    float* sc2     = ws + 640;               // 64
    float* sh2     = ws + 704;               // 64
    int*   ticket1 = (int*)(ws + 768);
    int*   ticket2 = (int*)(ws + 769);
    float* dinv    = ws + 784;               // N (16B aligned)
    int*   deg     = (int*)(dinv + N);       // N (aliased as cursor after scan)
    int*   cursor  = deg;
    int*   row_ptr = deg + N;                // N+16
    int*   tilesums = row_ptr + N + 16;      // 256
    int*   csr_src = tilesums + 256;         // E
    ushort* wfrag1 = (ushort*)(csr_src + E);        // 16384 bf16
    ushort* wfrag2 = wfrag1 + 16384;                // 8192 bf16
    ushort* h1     = wfrag2 + 8192;                 // N*128 bf16 (dinv-prescaled)
    ushort* bufB   = h1 + (size_t)N * HID_C;        // N*128 bf16
    ushort* h2     = bufB + (size_t)N * HID_C;      // N*64 bf16 (dinv-prescaled)
    ushort* agg2b  = h2 + (size_t)N * OUT_C2;       // N*64 bf16

    const int numTiles = (N + 1023) / 1024;  // 98 <= 256
    const int nbGemm1 = (N / 16 + 3) / 4;    // 1563

    init_kernel<<<(N + 255) / 256, 256, 0, stream>>>(ws, deg, N);
    degree_wre_kernel<<<NB_DEG + 12, 256, 0, stream>>>(dst, deg, E, gsz,
                                                       W1, W2, wfrag1, wfrag2);
    scan1_kernel<<<numTiles, 256, 0, stream>>>(deg, row_ptr, tilesums, dinv, N);
    scan_fin_kernel<<<(N + 255) / 256, 256, 0, stream>>>(row_ptr, cursor, tilesums, numTiles, N);

    // Fused: CSR placement + GEMM1 (independent; overlap in one dispatch)
    csr_gemm1_kernel<<<NB_CSR + nbGemm1, 256, 0, stream>>>(
        src, dst, cursor, csr_src, E, gsz, x, wfrag1, h1, dinv, N);

    aggregate_kernel<HID_C><<<(N + 3) / 4, 256, 0, stream>>>(
        h1, row_ptr, csr_src, dinv, bufB, N);
    stats_prep_kernel<HID_C><<<256, 256, 0, stream>>>(
        bufB, stats1, gamma1, beta1, sc1, sh1, ticket1, 256, N);

    mfma_gemm_kernel<OUT_C2, true><<<nbGemm1, 256, 0, stream>>>(
        bufB, wfrag2, h2, dinv, sc1, sh1, N);
    aggregate_kernel<OUT_C2><<<(N + 3) / 4, 256, 0, stream>>>(
        h2, row_ptr, csr_src, dinv, agg2b, N);
    stats_prep_kernel<OUT_C2><<<256, 256, 0, stream>>>(
        agg2b, stats2, gamma2, beta2, sc2, sh2, ticket2, 256, N);

    bn_apply_kernel<<<2048, 256, 0, stream>>>(agg2b, (float*)d_out, sc2, sh2, N);
}

// Round 10
// 406.340 us; speedup vs baseline: 1.0416x; 1.0416x over previous
//
#include <hip/hip_runtime.h>
#include <hip/hip_bf16.h>

// GNN decoder: 2x (GCNConv -> BatchNorm[-> ReLU]) on N=100000 nodes, E=1.6M edges.
// Round 10: bucketed two-phase CSR build replaces grouped atomic placement.
//   A: bucket (d>>8) histogram via LDS -> global counts (+ weight reorder rides).
//   scan: bucket bases (1 block); B: scatter (s,d) pairs bucket-contiguously
//   (LDS hist + per-bucket block reserve -> monotone positions, no 4B-random
//   write amplification); C: per-bucket LDS count/scan -> dinv, row_ptr,
//   csr_src all written coalesced / within L2-resident 16KB spans.
// r9 falsified NT-eviction theory (WRITE unchanged) and csr+gemm fusion
// (in-order dispatch = serialization). pairs buffer aliases h2/agg2b region.
// Carries: one-wave-per-node aggregates at ~3.8TB/s gather ceiling (r5/r7),
// stats+bnprep ticket fusion (r7), dinv-prescaled GEMMs (r4), bf16
// intermediates + no-LDS MFMA GEMMs (r3), CSR gather (r2), BN bias cancel (r1).

#define IN_C 128
#define HID_C 128
#define OUT_C2 64
#define BN_EPS 1e-5f

typedef __attribute__((ext_vector_type(8))) short short8v;
typedef __attribute__((ext_vector_type(4))) float float4v;
typedef __attribute__((ext_vector_type(4))) int int4v;

__device__ inline ushort f2bf(float f) {
    union { float f; unsigned u; } x; x.f = f;
    return (ushort)((x.u + 0x7fffu + ((x.u >> 16) & 1u)) >> 16);  // RNE
}
__device__ inline float bf2f(ushort u) {
    union { unsigned u; float f; } x; x.u = ((unsigned)u) << 16;
    return x.f;
}

// zero stats/tickets + bucket counts (ws words [0,1296))
__global__ void init_kernel(float* __restrict__ ws) {
    int i = blockIdx.x * blockDim.x + threadIdx.x;
    if (i < 1296) ws[i] = 0.0f;
}

// W[128][OC] f32 -> fragment-ordered bf16
template <int OC>
__device__ inline void wreorder_impl(const float* __restrict__ W,
                                     ushort* __restrict__ wfrag, int t) {
    constexpr int NCT = OC / 16;
    int lane = t & 63;
    int rest = t >> 6;
    int ct = rest % NCT;
    int kk = rest / NCT;
    int col = ct * 16 + (lane & 15);
    int krow = kk * 32 + (lane >> 4) * 8;
    ushort tmp[8];
    #pragma unroll
    for (int e = 0; e < 8; ++e)
        tmp[e] = f2bf(W[(size_t)(krow + e) * OC + col]);
    uint4 st;
    st.x = (uint)tmp[0] | ((uint)tmp[1] << 16);
    st.y = (uint)tmp[2] | ((uint)tmp[3] << 16);
    st.z = (uint)tmp[4] | ((uint)tmp[5] << 16);
    st.w = (uint)tmp[6] | ((uint)tmp[7] << 16);
    *(uint4*)&wfrag[(size_t)t * 8] = st;
}

// Phase A: bucket histogram (LDS) -> global bcnt. Blocks >= nbA do wreorder.
__global__ __launch_bounds__(256) void bucket_count_kernel(
    const int* __restrict__ dst, int* __restrict__ bcnt, int E, int nbA,
    const float* __restrict__ W1, const float* __restrict__ W2,
    ushort* __restrict__ wf1, ushort* __restrict__ wf2)
{
    if (blockIdx.x >= nbA) {
        int b = blockIdx.x - nbA;
        if (b < 8) wreorder_impl<HID_C>(W1, wf1, b * 256 + threadIdx.x);
        else       wreorder_impl<OUT_C2>(W2, wf2, (b - 8) * 256 + threadIdx.x);
        return;
    }
    __shared__ int h[512];
    int t = threadIdx.x;
    h[t] = 0; h[t + 256] = 0;
    __syncthreads();
    int i0 = blockIdx.x * 1024 + t * 4;
    if (i0 < E) {  // E % 4 == 0
        int4v d = __builtin_nontemporal_load((const int4v*)&dst[i0]);
        atomicAdd(&h[d.x >> 8], 1);
        atomicAdd(&h[d.y >> 8], 1);
        atomicAdd(&h[d.z >> 8], 1);
        atomicAdd(&h[d.w >> 8], 1);
    }
    __syncthreads();
    if (h[t])       atomicAdd(&bcnt[t], h[t]);
    if (h[t + 256]) atomicAdd(&bcnt[t + 256], h[t + 256]);
}

// Exclusive scan over 512 bucket counts -> bbase; bcnt becomes phase-B cursor.
__global__ __launch_bounds__(256) void bucket_scan_kernel(
    int* __restrict__ bcnt, int* __restrict__ bbase,
    int* __restrict__ row_ptr, int E, int N)
{
    __shared__ int sd[512];
    int t = threadIdx.x;
    int a = bcnt[t], b = bcnt[t + 256];
    sd[t] = a; sd[t + 256] = b;
    __syncthreads();
    for (int off = 1; off < 512; off <<= 1) {
        int v0 = (t >= off) ? sd[t - off] : 0;
        int v1 = sd[t + 256 - off];   // t+256 >= off always (off <= 256)
        __syncthreads();
        sd[t] += v0; sd[t + 256] += v1;
        __syncthreads();
    }
    int e0 = sd[t] - a, e1 = sd[t + 256] - b;
    bbase[t] = e0; bbase[t + 256] = e1;
    bcnt[t] = e0; bcnt[t + 256] = e1;   // cursor for phase B
    if (t == 0) row_ptr[N] = E;
}

// Phase B: scatter (src,dst) into bucket-contiguous pairs[] regions.
// LDS hist + one global reserve per bucket per block -> monotone write positions.
__global__ __launch_bounds__(256) void bucket_scatter_kernel(
    const int* __restrict__ src, const int* __restrict__ dst,
    int* __restrict__ bcursor, int2* __restrict__ pairs, int E)
{
    __shared__ int h[512];
    __shared__ int gb[512];
    int t = threadIdx.x;
    h[t] = 0; h[t + 256] = 0;
    __syncthreads();
    int i0 = blockIdx.x * 1024 + t * 4;
    bool act = i0 < E;
    int4v d, s;
    int bk0 = 0, bk1 = 0, bk2 = 0, bk3 = 0, r0 = 0, r1 = 0, r2 = 0, r3 = 0;
    if (act) {
        d = __builtin_nontemporal_load((const int4v*)&dst[i0]);
        s = __builtin_nontemporal_load((const int4v*)&src[i0]);
        bk0 = d.x >> 8; r0 = atomicAdd(&h[bk0], 1);
        bk1 = d.y >> 8; r1 = atomicAdd(&h[bk1], 1);
        bk2 = d.z >> 8; r2 = atomicAdd(&h[bk2], 1);
        bk3 = d.w >> 8; r3 = atomicAdd(&h[bk3], 1);
    }
    __syncthreads();
    if (h[t])       gb[t] = atomicAdd(&bcursor[t], h[t]);
    if (h[t + 256]) gb[t + 256] = atomicAdd(&bcursor[t + 256], h[t + 256]);
    __syncthreads();
    if (act) {
        pairs[gb[bk0] + r0] = make_int2(s.x, d.x);
        pairs[gb[bk1] + r1] = make_int2(s.y, d.y);
        pairs[gb[bk2] + r2] = make_int2(s.z, d.z);
        pairs[gb[bk3] + r3] = make_int2(s.w, d.w);
    }
}

// Phase C: one block per bucket (256 nodes, ~4K edges, L2-resident).
// Emits dinv + row_ptr coalesced; csr_src placed within a 16KB span.
__global__ __launch_bounds__(256) void bucket_csr_kernel(
    const int2* __restrict__ pairs, const int* __restrict__ bbase,
    int* __restrict__ csr_src, int* __restrict__ row_ptr,
    float* __restrict__ dinv, int N)
{
    __shared__ int cnt[256];
    __shared__ int sd[256];
    int t = threadIdx.x;
    int node0 = blockIdx.x << 8;
    int base = bbase[blockIdx.x], end = bbase[blockIdx.x + 1];
    cnt[t] = 0;
    __syncthreads();
    for (int i = base + t; i < end; i += 256)
        atomicAdd(&cnt[pairs[i].y & 255], 1);
    __syncthreads();
    int myc = cnt[t];
    sd[t] = myc;
    __syncthreads();
    for (int off = 1; off < 256; off <<= 1) {
        int v = (t >= off) ? sd[t - off] : 0;
        __syncthreads();
        sd[t] += v;
        __syncthreads();
    }
    int ofs = sd[t] - myc;  // exclusive
    int node = node0 + t;
    if (node < N) {
        row_ptr[node] = base + ofs;
        dinv[node] = rsqrtf((float)myc + 1.0f);  // +1 self-loop
    }
    cnt[t] = ofs;           // becomes intra-bucket cursor
    __syncthreads();
    for (int i = base + t; i < end; i += 256) {
        int2 p = pairs[i];
        int pos = atomicAdd(&cnt[p.y & 255], 1);
        csr_src[base + pos] = p.x;
    }
}

// MFMA GEMM: Y[N][OC] bf16 = dinv[row] * (A @ W). No LDS.
template <int OC, bool BN_IN>
__global__ __launch_bounds__(256) void mfma_gemm_kernel(
    const void* __restrict__ Xv, const ushort* __restrict__ wfrag,
    ushort* __restrict__ Y, const float* __restrict__ dinv,
    const float* __restrict__ sc, const float* __restrict__ sh, int N)
{
    constexpr int NCT = OC / 16;
    int wave = (blockIdx.x * 256 + threadIdx.x) >> 6;
    int lane = threadIdx.x & 63;
    int row16 = wave * 16;
    if (row16 >= N) return;
    int r = lane & 15;
    int g = lane >> 4;
    int row = row16 + r;

    float4v acc[NCT];
    #pragma unroll
    for (int ct = 0; ct < NCT; ++ct) acc[ct] = (float4v){0.f, 0.f, 0.f, 0.f};

    const short8v* wf = (const short8v*)wfrag;

    #pragma unroll
    for (int kk = 0; kk < 4; ++kk) {
        int k0 = kk * 32 + g * 8;
        short8v a;
        if constexpr (!BN_IN) {
            const float* xp = (const float*)Xv + (size_t)row * 128 + k0;
            float4 x0 = *(const float4*)xp;
            float4 x1 = *(const float4*)(xp + 4);
            a[0] = (short)f2bf(x0.x); a[1] = (short)f2bf(x0.y);
            a[2] = (short)f2bf(x0.z); a[3] = (short)f2bf(x0.w);
            a[4] = (short)f2bf(x1.x); a[5] = (short)f2bf(x1.y);
            a[6] = (short)f2bf(x1.z); a[7] = (short)f2bf(x1.w);
        } else {
            const ushort* xp = (const ushort*)Xv + (size_t)row * 128 + k0;
            uint4 v = *(const uint4*)xp;
            float4 s0 = *(const float4*)&sc[k0];
            float4 s1 = *(const float4*)&sc[k0 + 4];
            float4 h0 = *(const float4*)&sh[k0];
            float4 h1 = *(const float4*)&sh[k0 + 4];
            a[0] = (short)f2bf(fmaxf(fmaf(bf2f((ushort)(v.x & 0xffff)), s0.x, h0.x), 0.f));
            a[1] = (short)f2bf(fmaxf(fmaf(bf2f((ushort)(v.x >> 16)),    s0.y, h0.y), 0.f));
            a[2] = (short)f2bf(fmaxf(fmaf(bf2f((ushort)(v.y & 0xffff)), s0.z, h0.z), 0.f));
            a[3] = (short)f2bf(fmaxf(fmaf(bf2f((ushort)(v.y >> 16)),    s0.w, h0.w), 0.f));
            a[4] = (short)f2bf(fmaxf(fmaf(bf2f((ushort)(v.z & 0xffff)), s1.x, h1.x), 0.f));
            a[5] = (short)f2bf(fmaxf(fmaf(bf2f((ushort)(v.z >> 16)),    s1.y, h1.y), 0.f));
            a[6] = (short)f2bf(fmaxf(fmaf(bf2f((ushort)(v.w & 0xffff)), s1.z, h1.z), 0.f));
            a[7] = (short)f2bf(fmaxf(fmaf(bf2f((ushort)(v.w >> 16)),    s1.w, h1.w), 0.f));
        }
        #pragma unroll
        for (int ct = 0; ct < NCT; ++ct) {
            short8v b = wf[((size_t)(kk * NCT + ct)) * 64 + lane];
            acc[ct] = __builtin_amdgcn_mfma_f32_16x16x32_bf16(a, b, acc[ct], 0, 0, 0);
        }
    }
    float di[4];
    #pragma unroll
    for (int i = 0; i < 4; ++i) di[i] = dinv[row16 + g * 4 + i];
    #pragma unroll
    for (int ct = 0; ct < NCT; ++ct) {
        #pragma unroll
        for (int i = 0; i < 4; ++i) {
            int orow = row16 + g * 4 + i;
            Y[(size_t)orow * OC + ct * 16 + r] = f2bf(acc[ct][i] * di[i]);
        }
    }
}

// One wave per node, 2x-unrolled gather, bf16 out. NT csr_src reads.
template <int C>
__global__ __launch_bounds__(256) void aggregate_kernel(
    const ushort* __restrict__ h, const int* __restrict__ row_ptr,
    const int* __restrict__ csr_src, const float* __restrict__ dinv,
    ushort* __restrict__ out, int N)
{
    constexpr int TPN = C / 8;
    constexpr int PAR = 64 / TPN;
    int wid = (blockIdx.x * 256 + threadIdx.x) >> 6;
    if (wid >= N) return;
    int lane = threadIdx.x & 63;
    int part = lane / TPN;
    int c0 = (lane % TPN) * 8;
    float acc[8] = {0.f, 0.f, 0.f, 0.f, 0.f, 0.f, 0.f, 0.f};

    uint4 vself = make_uint4(0u, 0u, 0u, 0u);
    if (part == 0) vself = *(const uint4*)&h[(size_t)wid * C + c0];

    int e = row_ptr[wid] + part;
    int e1 = row_ptr[wid + 1];
    for (; e + PAR < e1; e += 2 * PAR) {
        int s0 = __builtin_nontemporal_load(&csr_src[e]);
        int s1 = __builtin_nontemporal_load(&csr_src[e + PAR]);
        uint4 v0 = *(const uint4*)&h[(size_t)s0 * C + c0];
        uint4 v1 = *(const uint4*)&h[(size_t)s1 * C + c0];
        acc[0] += bf2f((ushort)(v0.x & 0xffff)) + bf2f((ushort)(v1.x & 0xffff));
        acc[1] += bf2f((ushort)(v0.x >> 16))    + bf2f((ushort)(v1.x >> 16));
        acc[2] += bf2f((ushort)(v0.y & 0xffff)) + bf2f((ushort)(v1.y & 0xffff));
        acc[3] += bf2f((ushort)(v0.y >> 16))    + bf2f((ushort)(v1.y >> 16));
        acc[4] += bf2f((ushort)(v0.z & 0xffff)) + bf2f((ushort)(v1.z & 0xffff));
        acc[5] += bf2f((ushort)(v0.z >> 16))    + bf2f((ushort)(v1.z >> 16));
        acc[6] += bf2f((ushort)(v0.w & 0xffff)) + bf2f((ushort)(v1.w & 0xffff));
        acc[7] += bf2f((ushort)(v0.w >> 16))    + bf2f((ushort)(v1.w >> 16));
    }
    if (e < e1) {
        int s = __builtin_nontemporal_load(&csr_src[e]);
        uint4 v = *(const uint4*)&h[(size_t)s * C + c0];
        acc[0] += bf2f((ushort)(v.x & 0xffff));
        acc[1] += bf2f((ushort)(v.x >> 16));
        acc[2] += bf2f((ushort)(v.y & 0xffff));
        acc[3] += bf2f((ushort)(v.y >> 16));
        acc[4] += bf2f((ushort)(v.z & 0xffff));
        acc[5] += bf2f((ushort)(v.z >> 16));
        acc[6] += bf2f((ushort)(v.w & 0xffff));
        acc[7] += bf2f((ushort)(v.w >> 16));
    }
    if (part == 0) {
        acc[0] += bf2f((ushort)(vself.x & 0xffff));
        acc[1] += bf2f((ushort)(vself.x >> 16));
        acc[2] += bf2f((ushort)(vself.y & 0xffff));
        acc[3] += bf2f((ushort)(vself.y >> 16));
        acc[4] += bf2f((ushort)(vself.z & 0xffff));
        acc[5] += bf2f((ushort)(vself.z >> 16));
        acc[6] += bf2f((ushort)(vself.w & 0xffff));
        acc[7] += bf2f((ushort)(vself.w >> 16));
    }
    #pragma unroll
    for (int off = TPN; off < 64; off <<= 1) {
        #pragma unroll
        for (int j = 0; j < 8; ++j)
            acc[j] += __shfl_xor(acc[j], off, 64);
    }
    if (part == 0) {
        float dd = dinv[wid];
        uint4 st;
        #pragma unroll
        for (int j = 0; j < 8; ++j) acc[j] *= dd;
        st.x = (uint)f2bf(acc[0]) | ((uint)f2bf(acc[1]) << 16);
        st.y = (uint)f2bf(acc[2]) | ((uint)f2bf(acc[3]) << 16);
        st.z = (uint)f2bf(acc[4]) | ((uint)f2bf(acc[5]) << 16);
        st.w = (uint)f2bf(acc[6]) | ((uint)f2bf(acc[7]) << 16);
        *(uint4*)&out[(size_t)wid * C + c0] = st;
    }
}

// Per-channel sum & sumsq over bf16 rows + last-block BN scale/shift prep.
template <int C>
__global__ __launch_bounds__(256) void stats_prep_kernel(
    const ushort* __restrict__ h, float* __restrict__ sums /* [2C] */,
    const float* __restrict__ gamma, const float* __restrict__ beta,
    float* __restrict__ sc, float* __restrict__ sh,
    int* __restrict__ ticket, int nblocks, int N)
{
    constexpr int CG = C / 8;
    constexpr int RPB = 256 / CG;
    __shared__ float red[RPB][CG][16];
    __shared__ bool lastblk;
    int tid = threadIdx.x;
    int cg = tid % CG, rg = tid / CG;
    int c0 = cg * 8;
    float s[8] = {0.f,0.f,0.f,0.f,0.f,0.f,0.f,0.f};
    float q[8] = {0.f,0.f,0.f,0.f,0.f,0.f,0.f,0.f};
    for (int r = blockIdx.x * RPB + rg; r < N; r += gridDim.x * RPB) {
        uint4 v = *(const uint4*)&h[(size_t)r * C + c0];
        float f0 = bf2f((ushort)(v.x & 0xffff)), f1 = bf2f((ushort)(v.x >> 16));
        float f2 = bf2f((ushort)(v.y & 0xffff)), f3 = bf2f((ushort)(v.y >> 16));
        float f4 = bf2f((ushort)(v.z & 0xffff)), f5 = bf2f((ushort)(v.z >> 16));
        float f6 = bf2f((ushort)(v.w & 0xffff)), f7 = bf2f((ushort)(v.w >> 16));
        s[0]+=f0; s[1]+=f1; s[2]+=f2; s[3]+=f3; s[4]+=f4; s[5]+=f5; s[6]+=f6; s[7]+=f7;
        q[0]=fmaf(f0,f0,q[0]); q[1]=fmaf(f1,f1,q[1]); q[2]=fmaf(f2,f2,q[2]); q[3]=fmaf(f3,f3,q[3]);
        q[4]=fmaf(f4,f4,q[4]); q[5]=fmaf(f5,f5,q[5]); q[6]=fmaf(f6,f6,q[6]); q[7]=fmaf(f7,f7,q[7]);
    }
    #pragma unroll
    for (int j = 0; j < 8; ++j) { red[rg][cg][j] = s[j]; red[rg][cg][8 + j] = q[j]; }
    __syncthreads();
    if (rg == 0) {
        float a[16];
        #pragma unroll
        for (int i = 0; i < 16; ++i) a[i] = red[0][cg][i];
        for (int r2 = 1; r2 < RPB; ++r2)
            #pragma unroll
            for (int i = 0; i < 16; ++i) a[i] += red[r2][cg][i];
        #pragma unroll
        for (int j = 0; j < 8; ++j) {
            atomicAdd(&sums[c0 + j], a[j]);
            atomicAdd(&sums[C + c0 + j], a[8 + j]);
        }
    }
    __syncthreads();
    if (tid == 0) {
        __threadfence();
        int old = atomicAdd(ticket, 1);
        lastblk = (old == nblocks - 1);
    }
    __syncthreads();
    if (lastblk && tid < C) {
        float sv = atomicAdd(&sums[tid], 0.0f);        // coherent reads
        float qv = atomicAdd(&sums[C + tid], 0.0f);
        float invN = 1.0f / (float)N;
        float mu = sv * invN;
        float var = qv * invN - mu * mu;
        float scl = rsqrtf(var + BN_EPS) * gamma[tid];
        sc[tid] = scl;
        sh[tid] = beta[tid] - mu * scl;
    }
}

// BN2 apply: bf16 in -> f32 out, 8 channels per thread
__global__ void bn_apply_kernel(const ushort* __restrict__ in, float* __restrict__ out,
                                const float* __restrict__ sc, const float* __restrict__ sh,
                                int N)
{
    int total = N * (OUT_C2 / 8);
    int i = blockIdx.x * blockDim.x + threadIdx.x;
    int stride = gridDim.x * blockDim.x;
    for (; i < total; i += stride) {
        int c0 = (i & 7) * 8;
        uint4 v = *(const uint4*)&in[(size_t)i * 8];
        float4 s0 = *(const float4*)&sc[c0];
        float4 s1 = *(const float4*)&sc[c0 + 4];
        float4 h0 = *(const float4*)&sh[c0];
        float4 h1 = *(const float4*)&sh[c0 + 4];
        float4 o0, o1;
        o0.x = fmaf(bf2f((ushort)(v.x & 0xffff)), s0.x, h0.x);
        o0.y = fmaf(bf2f((ushort)(v.x >> 16)),    s0.y, h0.y);
        o0.z = fmaf(bf2f((ushort)(v.y & 0xffff)), s0.z, h0.z);
        o0.w = fmaf(bf2f((ushort)(v.y >> 16)),    s0.w, h0.w);
        o1.x = fmaf(bf2f((ushort)(v.z & 0xffff)), s1.x, h1.x);
        o1.y = fmaf(bf2f((ushort)(v.z >> 16)),    s1.y, h1.y);
        o1.z = fmaf(bf2f((ushort)(v.w & 0xffff)), s1.z, h1.z);
        o1.w = fmaf(bf2f((ushort)(v.w >> 16)),    s1.w, h1.w);
        *(float4*)&out[(size_t)i * 8] = o0;
        *(float4*)&out[(size_t)i * 8 + 4] = o1;
    }
}

extern "C" void kernel_launch(void* const* d_in, const int* in_sizes, int n_in,
                              void* d_out, int out_size, void* d_ws, size_t ws_size,
                              hipStream_t stream) {
    const float* x      = (const float*)d_in[0];
    const int*   ei     = (const int*)d_in[1];
    const float* W1     = (const float*)d_in[2];
    // d_in[3] = b1: cancels in BN1 -> skipped
    const float* gamma1 = (const float*)d_in[4];
    const float* beta1  = (const float*)d_in[5];
    const float* W2     = (const float*)d_in[6];
    // d_in[7] = b2: cancels in BN2 -> skipped
    const float* gamma2 = (const float*)d_in[8];
    const float* beta2  = (const float*)d_in[9];

    const int N = in_sizes[0] / IN_C;   // 100000 (divisible by 16)
    const int E = in_sizes[1] / 2;      // 1600000 (divisible by 4)
    const int* src = ei;
    const int* dst = ei + E;
    const int nbA   = (E + 1023) / 1024;   // 1563
    const int nbuck = (N + 255) >> 8;      // 391 (<= 512)

    // ws layout (4B words):
    float* ws      = (float*)d_ws;
    float* stats1  = ws;                     // 256
    float* stats2  = ws + 256;               // 128
    float* sc1     = ws + 384;               // 128
    float* sh1     = ws + 512;               // 128
    float* sc2     = ws + 640;               // 64
    float* sh2     = ws + 704;               // 64
    int*   ticket1 = (int*)(ws + 768);
    int*   ticket2 = (int*)(ws + 769);
    int*   bcnt    = (int*)(ws + 784);       // 512 (becomes phase-B cursor)
    int*   bbase   = (int*)(ws + 1296);      // 513
    float* dinv    = ws + 1824;              // N (16B aligned)
    int*   row_ptr = (int*)(dinv + N);       // N+16
    int*   csr_src = row_ptr + N + 16;       // E
    ushort* wfrag1 = (ushort*)(csr_src + E);        // 16384 bf16
    ushort* wfrag2 = wfrag1 + 16384;                // 8192 bf16
    ushort* h1     = wfrag2 + 8192;                 // N*128 bf16 (dinv-prescaled)
    ushort* bufB   = h1 + (size_t)N * HID_C;        // N*128 bf16
    ushort* h2     = bufB + (size_t)N * HID_C;      // N*64 bf16 (dinv-prescaled)
    ushort* agg2b  = h2 + (size_t)N * OUT_C2;       // N*64 bf16
    int2*  pairs   = (int2*)h2;   // alias: E*8B <= (h2+agg2b) 25.6MB; dead before gemm2

    const int nbGemm = (N / 16 + 3) / 4;    // 1563

    init_kernel<<<6, 256, 0, stream>>>(ws);
    bucket_count_kernel<<<nbA + 12, 256, 0, stream>>>(dst, bcnt, E, nbA,
                                                      W1, W2, wfrag1, wfrag2);
    bucket_scan_kernel<<<1, 256, 0, stream>>>(bcnt, bbase, row_ptr, E, N);
    bucket_scatter_kernel<<<nbA, 256, 0, stream>>>(src, dst, bcnt, pairs, E);
    bucket_csr_kernel<<<nbuck, 256, 0, stream>>>(pairs, bbase, csr_src, row_ptr,
                                                 dinv, N);

    // Layer 1
    mfma_gemm_kernel<HID_C, false><<<nbGemm, 256, 0, stream>>>(
        x, wfrag1, h1, dinv, nullptr, nullptr, N);
    aggregate_kernel<HID_C><<<(N + 3) / 4, 256, 0, stream>>>(
        h1, row_ptr, csr_src, dinv, bufB, N);
    stats_prep_kernel<HID_C><<<256, 256, 0, stream>>>(
        bufB, stats1, gamma1, beta1, sc1, sh1, ticket1, 256, N);

    // Layer 2
    mfma_gemm_kernel<OUT_C2, true><<<nbGemm, 256, 0, stream>>>(
        bufB, wfrag2, h2, dinv, sc1, sh1, N);
    aggregate_kernel<OUT_C2><<<(N + 3) / 4, 256, 0, stream>>>(
        h2, row_ptr, csr_src, dinv, agg2b, N);
    stats_prep_kernel<OUT_C2><<<256, 256, 0, stream>>>(
        agg2b, stats2, gamma2, beta2, sc2, sh2, ticket2, 256, N);

    bn_apply_kernel<<<2048, 256, 0, stream>>>(agg2b, (float*)d_out, sc2, sh2, N);
}

// Round 11
// 396.511 us; speedup vs baseline: 1.0674x; 1.0248x over previous
//
#include <hip/hip_runtime.h>
#include <hip/hip_bf16.h>

// GNN decoder: 2x (GCNConv -> BatchNorm[-> ReLU]) on N=100000 nodes, E=1.6M edges.
// Round 11: launch consolidation 13 -> 10. bucket_scan folded into scatter/csr
// (redundant 512-elem LDS scans + separate zeroed cursor). bn_apply fused into
// stats2 via resident-256-block ticket+spin (sc2/sh2 published with coherent
// atomics). NT loads for the read-once f32 x stream in GEMM1.
// Carries: bucketed two-phase CSR build (r10), one-wave-per-node aggregates at
// ~3.8TB/s gather ceiling (r5), stats+bnprep ticket fusion (r7), dinv-prescaled
// GEMMs (r4), bf16 intermediates + no-LDS MFMA GEMMs (r3), CSR gather (r2),
// BN bias cancellation (r1).

#define IN_C 128
#define HID_C 128
#define OUT_C2 64
#define BN_EPS 1e-5f

typedef __attribute__((ext_vector_type(8))) short short8v;
typedef __attribute__((ext_vector_type(4))) float float4v;
typedef __attribute__((ext_vector_type(4))) int int4v;

__device__ inline ushort f2bf(float f) {
    union { float f; unsigned u; } x; x.f = f;
    return (ushort)((x.u + 0x7fffu + ((x.u >> 16) & 1u)) >> 16);  // RNE
}
__device__ inline float bf2f(ushort u) {
    union { unsigned u; float f; } x; x.u = ((unsigned)u) << 16;
    return x.f;
}

// zero stats/sc/sh/tickets/flag + bcnt + bcursor (ws words [0,1808))
__global__ void init_kernel(float* __restrict__ ws) {
    int i = blockIdx.x * blockDim.x + threadIdx.x;
    if (i < 1808) ws[i] = 0.0f;
}

// W[128][OC] f32 -> fragment-ordered bf16
template <int OC>
__device__ inline void wreorder_impl(const float* __restrict__ W,
                                     ushort* __restrict__ wfrag, int t) {
    constexpr int NCT = OC / 16;
    int lane = t & 63;
    int rest = t >> 6;
    int ct = rest % NCT;
    int kk = rest / NCT;
    int col = ct * 16 + (lane & 15);
    int krow = kk * 32 + (lane >> 4) * 8;
    ushort tmp[8];
    #pragma unroll
    for (int e = 0; e < 8; ++e)
        tmp[e] = f2bf(W[(size_t)(krow + e) * OC + col]);
    uint4 st;
    st.x = (uint)tmp[0] | ((uint)tmp[1] << 16);
    st.y = (uint)tmp[2] | ((uint)tmp[3] << 16);
    st.z = (uint)tmp[4] | ((uint)tmp[5] << 16);
    st.w = (uint)tmp[6] | ((uint)tmp[7] << 16);
    *(uint4*)&wfrag[(size_t)t * 8] = st;
}

// Phase A: bucket histogram (LDS) -> global bcnt. Blocks >= nbA do wreorder.
__global__ __launch_bounds__(256) void bucket_count_kernel(
    const int* __restrict__ dst, int* __restrict__ bcnt, int E, int nbA,
    const float* __restrict__ W1, const float* __restrict__ W2,
    ushort* __restrict__ wf1, ushort* __restrict__ wf2)
{
    if (blockIdx.x >= nbA) {
        int b = blockIdx.x - nbA;
        if (b < 8) wreorder_impl<HID_C>(W1, wf1, b * 256 + threadIdx.x);
        else       wreorder_impl<OUT_C2>(W2, wf2, (b - 8) * 256 + threadIdx.x);
        return;
    }
    __shared__ int h[512];
    int t = threadIdx.x;
    h[t] = 0; h[t + 256] = 0;
    __syncthreads();
    int i0 = blockIdx.x * 1024 + t * 4;
    if (i0 < E) {  // E % 4 == 0
        int4v d = __builtin_nontemporal_load((const int4v*)&dst[i0]);
        atomicAdd(&h[d.x >> 8], 1);
        atomicAdd(&h[d.y >> 8], 1);
        atomicAdd(&h[d.z >> 8], 1);
        atomicAdd(&h[d.w >> 8], 1);
    }
    __syncthreads();
    if (h[t])       atomicAdd(&bcnt[t], h[t]);
    if (h[t + 256]) atomicAdd(&bcnt[t + 256], h[t + 256]);
}

// Phase B: scatter (src,dst) into bucket-contiguous pairs[] regions.
// Each block redundantly scans bcnt (512) in LDS for bucket bases; per-bucket
// block reserve via bcursor -> monotone write positions (no 4B-random writes).
__global__ __launch_bounds__(256) void bucket_scatter_kernel(
    const int* __restrict__ src, const int* __restrict__ dst,
    const int* __restrict__ bcnt, int* __restrict__ bcursor,
    int2* __restrict__ pairs, int E)
{
    __shared__ int bs[512];
    __shared__ int h[512];
    __shared__ int gb[512];
    int t = threadIdx.x;
    // exclusive scan of bcnt -> bs
    int a = bcnt[t], b = bcnt[t + 256];
    bs[t] = a; bs[t + 256] = b;
    __syncthreads();
    for (int off = 1; off < 512; off <<= 1) {
        int v0 = (t >= off) ? bs[t - off] : 0;
        int v1 = bs[t + 256 - off];
        __syncthreads();
        bs[t] += v0; bs[t + 256] += v1;
        __syncthreads();
    }
    int e0 = bs[t] - a, e1 = bs[t + 256] - b;
    __syncthreads();
    bs[t] = e0; bs[t + 256] = e1;
    h[t] = 0; h[t + 256] = 0;
    __syncthreads();
    int i0 = blockIdx.x * 1024 + t * 4;
    bool act = i0 < E;
    int4v d, s;
    int bk0 = 0, bk1 = 0, bk2 = 0, bk3 = 0, r0 = 0, r1 = 0, r2 = 0, r3 = 0;
    if (act) {
        d = __builtin_nontemporal_load((const int4v*)&dst[i0]);
        s = __builtin_nontemporal_load((const int4v*)&src[i0]);
        bk0 = d.x >> 8; r0 = atomicAdd(&h[bk0], 1);
        bk1 = d.y >> 8; r1 = atomicAdd(&h[bk1], 1);
        bk2 = d.z >> 8; r2 = atomicAdd(&h[bk2], 1);
        bk3 = d.w >> 8; r3 = atomicAdd(&h[bk3], 1);
    }
    __syncthreads();
    if (h[t])       gb[t] = bs[t] + atomicAdd(&bcursor[t], h[t]);
    if (h[t + 256]) gb[t + 256] = bs[t + 256] + atomicAdd(&bcursor[t + 256], h[t + 256]);
    __syncthreads();
    if (act) {
        pairs[gb[bk0] + r0] = make_int2(s.x, d.x);
        pairs[gb[bk1] + r1] = make_int2(s.y, d.y);
        pairs[gb[bk2] + r2] = make_int2(s.z, d.z);
        pairs[gb[bk3] + r3] = make_int2(s.w, d.w);
    }
}

// Phase C: one block per bucket (256 nodes, ~4K edges, L2-resident).
// Redundant LDS scan of bcnt for bucket bases; emits dinv + row_ptr coalesced;
// csr_src placed within a 16KB span.
__global__ __launch_bounds__(256) void bucket_csr_kernel(
    const int2* __restrict__ pairs, const int* __restrict__ bcnt,
    int* __restrict__ csr_src, int* __restrict__ row_ptr,
    float* __restrict__ dinv, int E, int N)
{
    __shared__ int bs[512];
    __shared__ int cnt[256];
    __shared__ int sd[256];
    int t = threadIdx.x;
    // exclusive scan of bcnt -> bs
    int a = bcnt[t], b = bcnt[t + 256];
    bs[t] = a; bs[t + 256] = b;
    __syncthreads();
    for (int off = 1; off < 512; off <<= 1) {
        int v0 = (t >= off) ? bs[t - off] : 0;
        int v1 = bs[t + 256 - off];
        __syncthreads();
        bs[t] += v0; bs[t + 256] += v1;
        __syncthreads();
    }
    int e0 = bs[t] - a, e1 = bs[t + 256] - b;
    __syncthreads();
    bs[t] = e0; bs[t + 256] = e1;
    __syncthreads();
    int node0 = blockIdx.x << 8;
    int base = bs[blockIdx.x];
    int end  = (blockIdx.x == 511) ? E : bs[blockIdx.x + 1];
    if (blockIdx.x == 0 && t == 0) row_ptr[N] = E;
    cnt[t] = 0;
    __syncthreads();
    for (int i = base + t; i < end; i += 256)
        atomicAdd(&cnt[pairs[i].y & 255], 1);
    __syncthreads();
    int myc = cnt[t];
    sd[t] = myc;
    __syncthreads();
    for (int off = 1; off < 256; off <<= 1) {
        int v = (t >= off) ? sd[t - off] : 0;
        __syncthreads();
        sd[t] += v;
        __syncthreads();
    }
    int ofs = sd[t] - myc;  // exclusive
    int node = node0 + t;
    if (node < N) {
        row_ptr[node] = base + ofs;
        dinv[node] = rsqrtf((float)myc + 1.0f);  // +1 self-loop
    }
    cnt[t] = ofs;           // becomes intra-bucket cursor
    __syncthreads();
    for (int i = base + t; i < end; i += 256) {
        int2 p = pairs[i];
        int pos = atomicAdd(&cnt[p.y & 255], 1);
        csr_src[base + pos] = p.x;
    }
}

// MFMA GEMM: Y[N][OC] bf16 = dinv[row] * (A @ W). No LDS. NT loads for f32 A.
template <int OC, bool BN_IN>
__global__ __launch_bounds__(256) void mfma_gemm_kernel(
    const void* __restrict__ Xv, const ushort* __restrict__ wfrag,
    ushort* __restrict__ Y, const float* __restrict__ dinv,
    const float* __restrict__ sc, const float* __restrict__ sh, int N)
{
    constexpr int NCT = OC / 16;
    int wave = (blockIdx.x * 256 + threadIdx.x) >> 6;
    int lane = threadIdx.x & 63;
    int row16 = wave * 16;
    if (row16 >= N) return;
    int r = lane & 15;
    int g = lane >> 4;
    int row = row16 + r;

    float4v acc[NCT];
    #pragma unroll
    for (int ct = 0; ct < NCT; ++ct) acc[ct] = (float4v){0.f, 0.f, 0.f, 0.f};

    const short8v* wf = (const short8v*)wfrag;

    #pragma unroll
    for (int kk = 0; kk < 4; ++kk) {
        int k0 = kk * 32 + g * 8;
        short8v a;
        if constexpr (!BN_IN) {
            const float* xp = (const float*)Xv + (size_t)row * 128 + k0;
            float4v x0 = __builtin_nontemporal_load((const float4v*)xp);
            float4v x1 = __builtin_nontemporal_load((const float4v*)(xp + 4));
            a[0] = (short)f2bf(x0[0]); a[1] = (short)f2bf(x0[1]);
            a[2] = (short)f2bf(x0[2]); a[3] = (short)f2bf(x0[3]);
            a[4] = (short)f2bf(x1[0]); a[5] = (short)f2bf(x1[1]);
            a[6] = (short)f2bf(x1[2]); a[7] = (short)f2bf(x1[3]);
        } else {
            const ushort* xp = (const ushort*)Xv + (size_t)row * 128 + k0;
            uint4 v = *(const uint4*)xp;
            float4 s0 = *(const float4*)&sc[k0];
            float4 s1 = *(const float4*)&sc[k0 + 4];
            float4 h0 = *(const float4*)&sh[k0];
            float4 h1 = *(const float4*)&sh[k0 + 4];
            a[0] = (short)f2bf(fmaxf(fmaf(bf2f((ushort)(v.x & 0xffff)), s0.x, h0.x), 0.f));
            a[1] = (short)f2bf(fmaxf(fmaf(bf2f((ushort)(v.x >> 16)),    s0.y, h0.y), 0.f));
            a[2] = (short)f2bf(fmaxf(fmaf(bf2f((ushort)(v.y & 0xffff)), s0.z, h0.z), 0.f));
            a[3] = (short)f2bf(fmaxf(fmaf(bf2f((ushort)(v.y >> 16)),    s0.w, h0.w), 0.f));
            a[4] = (short)f2bf(fmaxf(fmaf(bf2f((ushort)(v.z & 0xffff)), s1.x, h1.x), 0.f));
            a[5] = (short)f2bf(fmaxf(fmaf(bf2f((ushort)(v.z >> 16)),    s1.y, h1.y), 0.f));
            a[6] = (short)f2bf(fmaxf(fmaf(bf2f((ushort)(v.w & 0xffff)), s1.z, h1.z), 0.f));
            a[7] = (short)f2bf(fmaxf(fmaf(bf2f((ushort)(v.w >> 16)),    s1.w, h1.w), 0.f));
        }
        #pragma unroll
        for (int ct = 0; ct < NCT; ++ct) {
            short8v b = wf[((size_t)(kk * NCT + ct)) * 64 + lane];
            acc[ct] = __builtin_amdgcn_mfma_f32_16x16x32_bf16(a, b, acc[ct], 0, 0, 0);
        }
    }
    float di[4];
    #pragma unroll
    for (int i = 0; i < 4; ++i) di[i] = dinv[row16 + g * 4 + i];
    #pragma unroll
    for (int ct = 0; ct < NCT; ++ct) {
        #pragma unroll
        for (int i = 0; i < 4; ++i) {
            int orow = row16 + g * 4 + i;
            Y[(size_t)orow * OC + ct * 16 + r] = f2bf(acc[ct][i] * di[i]);
        }
    }
}

// One wave per node, 2x-unrolled gather, bf16 out. NT csr_src reads.
template <int C>
__global__ __launch_bounds__(256) void aggregate_kernel(
    const ushort* __restrict__ h, const int* __restrict__ row_ptr,
    const int* __restrict__ csr_src, const float* __restrict__ dinv,
    ushort* __restrict__ out, int N)
{
    constexpr int TPN = C / 8;
    constexpr int PAR = 64 / TPN;
    int wid = (blockIdx.x * 256 + threadIdx.x) >> 6;
    if (wid >= N) return;
    int lane = threadIdx.x & 63;
    int part = lane / TPN;
    int c0 = (lane % TPN) * 8;
    float acc[8] = {0.f, 0.f, 0.f, 0.f, 0.f, 0.f, 0.f, 0.f};

    uint4 vself = make_uint4(0u, 0u, 0u, 0u);
    if (part == 0) vself = *(const uint4*)&h[(size_t)wid * C + c0];

    int e = row_ptr[wid] + part;
    int e1 = row_ptr[wid + 1];
    for (; e + PAR < e1; e += 2 * PAR) {
        int s0 = __builtin_nontemporal_load(&csr_src[e]);
        int s1 = __builtin_nontemporal_load(&csr_src[e + PAR]);
        uint4 v0 = *(const uint4*)&h[(size_t)s0 * C + c0];
        uint4 v1 = *(const uint4*)&h[(size_t)s1 * C + c0];
        acc[0] += bf2f((ushort)(v0.x & 0xffff)) + bf2f((ushort)(v1.x & 0xffff));
        acc[1] += bf2f((ushort)(v0.x >> 16))    + bf2f((ushort)(v1.x >> 16));
        acc[2] += bf2f((ushort)(v0.y & 0xffff)) + bf2f((ushort)(v1.y & 0xffff));
        acc[3] += bf2f((ushort)(v0.y >> 16))    + bf2f((ushort)(v1.y >> 16));
        acc[4] += bf2f((ushort)(v0.z & 0xffff)) + bf2f((ushort)(v1.z & 0xffff));
        acc[5] += bf2f((ushort)(v0.z >> 16))    + bf2f((ushort)(v1.z >> 16));
        acc[6] += bf2f((ushort)(v0.w & 0xffff)) + bf2f((ushort)(v1.w & 0xffff));
        acc[7] += bf2f((ushort)(v0.w >> 16))    + bf2f((ushort)(v1.w >> 16));
    }
    if (e < e1) {
        int s = __builtin_nontemporal_load(&csr_src[e]);
        uint4 v = *(const uint4*)&h[(size_t)s * C + c0];
        acc[0] += bf2f((ushort)(v.x & 0xffff));
        acc[1] += bf2f((ushort)(v.x >> 16));
        acc[2] += bf2f((ushort)(v.y & 0xffff));
        acc[3] += bf2f((ushort)(v.y >> 16));
        acc[4] += bf2f((ushort)(v.z & 0xffff));
        acc[5] += bf2f((ushort)(v.z >> 16));
        acc[6] += bf2f((ushort)(v.w & 0xffff));
        acc[7] += bf2f((ushort)(v.w >> 16));
    }
    if (part == 0) {
        acc[0] += bf2f((ushort)(vself.x & 0xffff));
        acc[1] += bf2f((ushort)(vself.x >> 16));
        acc[2] += bf2f((ushort)(vself.y & 0xffff));
        acc[3] += bf2f((ushort)(vself.y >> 16));
        acc[4] += bf2f((ushort)(vself.z & 0xffff));
        acc[5] += bf2f((ushort)(vself.z >> 16));
        acc[6] += bf2f((ushort)(vself.w & 0xffff));
        acc[7] += bf2f((ushort)(vself.w >> 16));
    }
    #pragma unroll
    for (int off = TPN; off < 64; off <<= 1) {
        #pragma unroll
        for (int j = 0; j < 8; ++j)
            acc[j] += __shfl_xor(acc[j], off, 64);
    }
    if (part == 0) {
        float dd = dinv[wid];
        uint4 st;
        #pragma unroll
        for (int j = 0; j < 8; ++j) acc[j] *= dd;
        st.x = (uint)f2bf(acc[0]) | ((uint)f2bf(acc[1]) << 16);
        st.y = (uint)f2bf(acc[2]) | ((uint)f2bf(acc[3]) << 16);
        st.z = (uint)f2bf(acc[4]) | ((uint)f2bf(acc[5]) << 16);
        st.w = (uint)f2bf(acc[6]) | ((uint)f2bf(acc[7]) << 16);
        *(uint4*)&out[(size_t)wid * C + c0] = st;
    }
}

// Per-channel sum & sumsq over bf16 rows + last-block BN scale/shift prep (layer 1).
template <int C>
__global__ __launch_bounds__(256) void stats_prep_kernel(
    const ushort* __restrict__ h, float* __restrict__ sums /* [2C] */,
    const float* __restrict__ gamma, const float* __restrict__ beta,
    float* __restrict__ sc, float* __restrict__ sh,
    int* __restrict__ ticket, int nblocks, int N)
{
    constexpr int CG = C / 8;
    constexpr int RPB = 256 / CG;
    __shared__ float red[RPB][CG][16];
    __shared__ bool lastblk;
    int tid = threadIdx.x;
    int cg = tid % CG, rg = tid / CG;
    int c0 = cg * 8;
    float s[8] = {0.f,0.f,0.f,0.f,0.f,0.f,0.f,0.f};
    float q[8] = {0.f,0.f,0.f,0.f,0.f,0.f,0.f,0.f};
    for (int r = blockIdx.x * RPB + rg; r < N; r += gridDim.x * RPB) {
        uint4 v = *(const uint4*)&h[(size_t)r * C + c0];
        float f0 = bf2f((ushort)(v.x & 0xffff)), f1 = bf2f((ushort)(v.x >> 16));
        float f2 = bf2f((ushort)(v.y & 0xffff)), f3 = bf2f((ushort)(v.y >> 16));
        float f4 = bf2f((ushort)(v.z & 0xffff)), f5 = bf2f((ushort)(v.z >> 16));
        float f6 = bf2f((ushort)(v.w & 0xffff)), f7 = bf2f((ushort)(v.w >> 16));
        s[0]+=f0; s[1]+=f1; s[2]+=f2; s[3]+=f3; s[4]+=f4; s[5]+=f5; s[6]+=f6; s[7]+=f7;
        q[0]=fmaf(f0,f0,q[0]); q[1]=fmaf(f1,f1,q[1]); q[2]=fmaf(f2,f2,q[2]); q[3]=fmaf(f3,f3,q[3]);
        q[4]=fmaf(f4,f4,q[4]); q[5]=fmaf(f5,f5,q[5]); q[6]=fmaf(f6,f6,q[6]); q[7]=fmaf(f7,f7,q[7]);
    }
    #pragma unroll
    for (int j = 0; j < 8; ++j) { red[rg][cg][j] = s[j]; red[rg][cg][8 + j] = q[j]; }
    __syncthreads();
    if (rg == 0) {
        float a[16];
        #pragma unroll
        for (int i = 0; i < 16; ++i) a[i] = red[0][cg][i];
        for (int r2 = 1; r2 < RPB; ++r2)
            #pragma unroll
            for (int i = 0; i < 16; ++i) a[i] += red[r2][cg][i];
        #pragma unroll
        for (int j = 0; j < 8; ++j) {
            atomicAdd(&sums[c0 + j], a[j]);
            atomicAdd(&sums[C + c0 + j], a[8 + j]);
        }
    }
    __syncthreads();
    if (tid == 0) {
        __threadfence();
        int old = atomicAdd(ticket, 1);
        lastblk = (old == nblocks - 1);
    }
    __syncthreads();
    if (lastblk && tid < C) {
        float sv = atomicAdd(&sums[tid], 0.0f);        // coherent reads
        float qv = atomicAdd(&sums[C + tid], 0.0f);
        float invN = 1.0f / (float)N;
        float mu = sv * invN;
        float var = qv * invN - mu * mu;
        float scl = rsqrtf(var + BN_EPS) * gamma[tid];
        sc[tid] = scl;
        sh[tid] = beta[tid] - mu * scl;
    }
}

// Layer-2 stats + BN prep + fused BN apply (resident 256 blocks, ticket+spin).
__global__ __launch_bounds__(256) void stats2_bn_kernel(
    const ushort* __restrict__ h, float* __restrict__ sums /* [128] */,
    const float* __restrict__ gamma, const float* __restrict__ beta,
    float* __restrict__ sc, float* __restrict__ sh,
    int* __restrict__ ticket, int* __restrict__ flag,
    float* __restrict__ out, int nblocks, int N)
{
    constexpr int C = OUT_C2;
    constexpr int CG = C / 8;      // 8
    constexpr int RPB = 256 / CG;  // 32
    __shared__ float red[RPB][CG][16];
    __shared__ bool lastblk;
    __shared__ float lsc[C], lsh[C];
    int tid = threadIdx.x;
    int cg = tid % CG, rg = tid / CG;
    int c0 = cg * 8;
    float s[8] = {0.f,0.f,0.f,0.f,0.f,0.f,0.f,0.f};
    float q[8] = {0.f,0.f,0.f,0.f,0.f,0.f,0.f,0.f};
    for (int r = blockIdx.x * RPB + rg; r < N; r += gridDim.x * RPB) {
        uint4 v = *(const uint4*)&h[(size_t)r * C + c0];
        float f0 = bf2f((ushort)(v.x & 0xffff)), f1 = bf2f((ushort)(v.x >> 16));
        float f2 = bf2f((ushort)(v.y & 0xffff)), f3 = bf2f((ushort)(v.y >> 16));
        float f4 = bf2f((ushort)(v.z & 0xffff)), f5 = bf2f((ushort)(v.z >> 16));
        float f6 = bf2f((ushort)(v.w & 0xffff)), f7 = bf2f((ushort)(v.w >> 16));
        s[0]+=f0; s[1]+=f1; s[2]+=f2; s[3]+=f3; s[4]+=f4; s[5]+=f5; s[6]+=f6; s[7]+=f7;
        q[0]=fmaf(f0,f0,q[0]); q[1]=fmaf(f1,f1,q[1]); q[2]=fmaf(f2,f2,q[2]); q[3]=fmaf(f3,f3,q[3]);
        q[4]=fmaf(f4,f4,q[4]); q[5]=fmaf(f5,f5,q[5]); q[6]=fmaf(f6,f6,q[6]); q[7]=fmaf(f7,f7,q[7]);
    }
    #pragma unroll
    for (int j = 0; j < 8; ++j) { red[rg][cg][j] = s[j]; red[rg][cg][8 + j] = q[j]; }
    __syncthreads();
    if (rg == 0) {
        float a[16];
        #pragma unroll
        for (int i = 0; i < 16; ++i) a[i] = red[0][cg][i];
        for (int r2 = 1; r2 < RPB; ++r2)
            #pragma unroll
            for (int i = 0; i < 16; ++i) a[i] += red[r2][cg][i];
        #pragma unroll
        for (int j = 0; j < 8; ++j) {
            atomicAdd(&sums[c0 + j], a[j]);
            atomicAdd(&sums[C + c0 + j], a[8 + j]);
        }
    }
    __syncthreads();
    if (tid == 0) {
        __threadfence();
        int old = atomicAdd(ticket, 1);
        lastblk = (old == nblocks - 1);
    }
    __syncthreads();
    if (lastblk) {
        if (tid < C) {
            float sv = atomicAdd(&sums[tid], 0.0f);
            float qv = atomicAdd(&sums[C + tid], 0.0f);
            float invN = 1.0f / (float)N;
            float mu = sv * invN;
            float var = qv * invN - mu * mu;
            float scl = rsqrtf(var + BN_EPS) * gamma[tid];
            atomicAdd(&sc[tid], scl);               // sc/sh zeroed by init
            atomicAdd(&sh[tid], beta[tid] - mu * scl);
        }
        __syncthreads();
        if (tid == 0) { __threadfence(); atomicAdd(flag, 1); }
    }
    // all 256 blocks co-resident (1/CU) -> spin is deadlock-free
    if (tid == 0) {
        while (atomicAdd(flag, 0) == 0) __builtin_amdgcn_s_sleep(2);
    }
    __syncthreads();
    if (tid < C)          lsc[tid] = atomicAdd(&sc[tid], 0.0f);
    else if (tid < 2 * C) lsh[tid - C] = atomicAdd(&sh[tid - C], 0.0f);
    __syncthreads();
    // BN2 apply: bf16 in -> f32 out
    int total = N * (C / 8);
    for (int i = blockIdx.x * 256 + tid; i < total; i += gridDim.x * 256) {
        int cc = (i & 7) * 8;
        uint4 v = *(const uint4*)&h[(size_t)i * 8];
        float4 o0, o1;
        o0.x = fmaf(bf2f((ushort)(v.x & 0xffff)), lsc[cc + 0], lsh[cc + 0]);
        o0.y = fmaf(bf2f((ushort)(v.x >> 16)),    lsc[cc + 1], lsh[cc + 1]);
        o0.z = fmaf(bf2f((ushort)(v.y & 0xffff)), lsc[cc + 2], lsh[cc + 2]);
        o0.w = fmaf(bf2f((ushort)(v.y >> 16)),    lsc[cc + 3], lsh[cc + 3]);
        o1.x = fmaf(bf2f((ushort)(v.z & 0xffff)), lsc[cc + 4], lsh[cc + 4]);
        o1.y = fmaf(bf2f((ushort)(v.z >> 16)),    lsc[cc + 5], lsh[cc + 5]);
        o1.z = fmaf(bf2f((ushort)(v.w & 0xffff)), lsc[cc + 6], lsh[cc + 6]);
        o1.w = fmaf(bf2f((ushort)(v.w >> 16)),    lsc[cc + 7], lsh[cc + 7]);
        *(float4*)&out[(size_t)i * 8] = o0;
        *(float4*)&out[(size_t)i * 8 + 4] = o1;
    }
}

extern "C" void kernel_launch(void* const* d_in, const int* in_sizes, int n_in,
                              void* d_out, int out_size, void* d_ws, size_t ws_size,
                              hipStream_t stream) {
    const float* x      = (const float*)d_in[0];
    const int*   ei     = (const int*)d_in[1];
    const float* W1     = (const float*)d_in[2];
    // d_in[3] = b1: cancels in BN1 -> skipped
    const float* gamma1 = (const float*)d_in[4];
    const float* beta1  = (const float*)d_in[5];
    const float* W2     = (const float*)d_in[6];
    // d_in[7] = b2: cancels in BN2 -> skipped
    const float* gamma2 = (const float*)d_in[8];
    const float* beta2  = (const float*)d_in[9];

    const int N = in_sizes[0] / IN_C;   // 100000 (divisible by 16)
    const int E = in_sizes[1] / 2;      // 1600000 (divisible by 4)
    const int* src = ei;
    const int* dst = ei + E;
    const int nbA   = (E + 1023) / 1024;   // 1563
    const int nbuck = (N + 255) >> 8;      // 391 (<= 512)

    // ws layout (4B words):
    float* ws      = (float*)d_ws;
    float* stats1  = ws;                     // 256
    float* stats2  = ws + 256;               // 128
    float* sc1     = ws + 384;               // 128
    float* sh1     = ws + 512;               // 128
    float* sc2     = ws + 640;               // 64
    float* sh2     = ws + 704;               // 64
    int*   ticket1 = (int*)(ws + 768);
    int*   ticket2 = (int*)(ws + 769);
    int*   flag2   = (int*)(ws + 770);
    int*   bcnt    = (int*)(ws + 784);       // 512
    int*   bcursor = (int*)(ws + 1296);      // 512
    float* dinv    = ws + 1808;              // N (1808*4 % 16 == 0)
    int*   row_ptr = (int*)(dinv + N);       // N+16
    int*   csr_src = row_ptr + N + 16;       // E
    ushort* wfrag1 = (ushort*)(csr_src + E);        // 16384 bf16
    ushort* wfrag2 = wfrag1 + 16384;                // 8192 bf16
    ushort* h1     = wfrag2 + 8192;                 // N*128 bf16 (dinv-prescaled)
    ushort* bufB   = h1 + (size_t)N * HID_C;        // N*128 bf16
    ushort* h2     = bufB + (size_t)N * HID_C;      // N*64 bf16 (dinv-prescaled)
    ushort* agg2b  = h2 + (size_t)N * OUT_C2;       // N*64 bf16
    int2*  pairs   = (int2*)h2;   // alias: E*8B = 12.8MB <= h2+agg2b 25.6MB; dead before gemm2

    const int nbGemm = (N / 16 + 3) / 4;    // 1563

    init_kernel<<<8, 256, 0, stream>>>(ws);
    bucket_count_kernel<<<nbA + 12, 256, 0, stream>>>(dst, bcnt, E, nbA,
                                                      W1, W2, wfrag1, wfrag2);
    bucket_scatter_kernel<<<nbA, 256, 0, stream>>>(src, dst, bcnt, bcursor, pairs, E);
    bucket_csr_kernel<<<nbuck, 256, 0, stream>>>(pairs, bcnt, csr_src, row_ptr,
                                                 dinv, E, N);

    // Layer 1
    mfma_gemm_kernel<HID_C, false><<<nbGemm, 256, 0, stream>>>(
        x, wfrag1, h1, dinv, nullptr, nullptr, N);
    aggregate_kernel<HID_C><<<(N + 3) / 4, 256, 0, stream>>>(
        h1, row_ptr, csr_src, dinv, bufB, N);
    stats_prep_kernel<HID_C><<<256, 256, 0, stream>>>(
        bufB, stats1, gamma1, beta1, sc1, sh1, ticket1, 256, N);

    // Layer 2
    mfma_gemm_kernel<OUT_C2, true><<<nbGemm, 256, 0, stream>>>(
        bufB, wfrag2, h2, dinv, sc1, sh1, N);
    aggregate_kernel<OUT_C2><<<(N + 3) / 4, 256, 0, stream>>>(
        h2, row_ptr, csr_src, dinv, agg2b, N);
    stats2_bn_kernel<<<256, 256, 0, stream>>>(
        agg2b, stats2, gamma2, beta2, sc2, sh2, ticket2, flag2,
        (float*)d_out, 256, N);
}